// Round 1
// baseline (525.341 us; speedup 1.0000x reference)
//
#include <hip/hip_runtime.h>

// DeformConv fused pipeline, MI355X gfx950.
// Shapes (hard-coded per reference): B=2, Ci=Co=256, H=W=96.
// Kernels:
//  1) cvt_w9:        w_dcn fp32 -> bf16 [Co][Ci*9]
//  2) off_conv_part: 3x3 conv -> om partials (Ci split 4-way for occupancy)
//  3) prep_kernel:   sum partials + bias -> bilinear corner idx + weights (mask/valid folded)
//  4) dcn_gemm:      fused gather-sample + bf16 MFMA GEMM, out = W9 * S + b_dcn (pre-BN, fp32)
//  5) bn_stats:      per-channel mean/var -> scale/shift
//  6) bn_apply:      y = relu(out*scale + shift), float4 vectorized

typedef unsigned short ushort_t;
typedef unsigned int uint_t;
typedef __attribute__((ext_vector_type(8))) short bf16x8;
typedef __attribute__((ext_vector_type(4))) float f32x4;

#define HH 96
#define WW 96
#define HWSZ 9216
#define CI 256
#define CO 256
#define NB 2
#define NPIX 18432           // NB*HWSZ
#define KTOT 2304            // CI*9
#define BM 128
#define BN 64
#define BK 32
#define NCHUNK 72            // KTOT/BK
#define A_STRIDE 1040        // BM*8+16 bf16 elems; byte stride 2080 ≡ 32 (mod 128) -> bank-balanced
#define S_STRIDE 528         // BN*8+16 bf16 elems; byte stride 1056 ≡ 32 (mod 128)

__device__ __forceinline__ ushort_t f2bf(float f) {
  unsigned int u = __float_as_uint(f);
  u += 0x7fffu + ((u >> 16) & 1u);   // RNE
  return (ushort_t)(u >> 16);
}

// ---------------- 1) w_dcn -> bf16 ----------------
__global__ void cvt_w9(const float* __restrict__ w, ushort_t* __restrict__ o, int n) {
  int i = blockIdx.x * 256 + threadIdx.x;
  if (i < n) o[i] = f2bf(w[i]);
}

// ---------------- 2) offset conv partials ----------------
// om_part layout: [4 part][27 ch][NPIX]
__global__ void off_conv_part(const float* __restrict__ x, const float* __restrict__ w_off,
                              float* __restrict__ om_part) {
  int n = blockIdx.x * 256 + threadIdx.x;      // pixel, exact grid
  int part = blockIdx.y;                        // 0..3 -> ci chunk of 64
  int b = n / HWSZ;
  int hw = n - b * HWSZ;
  int h = hw / WW;
  int w = hw - h * WW;
  float acc[27];
#pragma unroll
  for (int i = 0; i < 27; ++i) acc[i] = 0.f;
  const float* xb = x + (size_t)b * CI * HWSZ;
  int ci0 = part * 64;
  for (int ci = ci0; ci < ci0 + 64; ++ci) {
    const float* xc = xb + (size_t)ci * HWSZ;
    float xv[9];
#pragma unroll
    for (int t = 0; t < 9; ++t) {
      int yy = h - 1 + t / 3;
      int xx = w - 1 + t % 3;
      bool ok = (yy >= 0) && (yy < HH) && (xx >= 0) && (xx < WW);
      xv[t] = ok ? xc[yy * WW + xx] : 0.f;
    }
    const float* wp = w_off + ci * 9;           // w_off[ch][ci][t] = w_off[ch*2304 + ci*9 + t]
#pragma unroll
    for (int ch = 0; ch < 27; ++ch) {
      const float* wc = wp + ch * 2304;
#pragma unroll
      for (int t = 0; t < 9; ++t) acc[ch] += xv[t] * wc[t];
    }
  }
  float* op = om_part + (size_t)part * 27 * NPIX;
#pragma unroll
  for (int ch = 0; ch < 27; ++ch) op[(size_t)ch * NPIX + n] = acc[ch];
}

// ---------------- 3) prep: coords -> corner idx + folded weights ----------------
// widx[n*9+k] = {i00|i01<<16, i10|i11<<16}; wwt[n*9+k] = {w00,w01,w10,w11} (mask+valid folded)
__global__ void prep_kernel(const float* __restrict__ om_part, const float* __restrict__ b_off,
                            uint2* __restrict__ widx, float4* __restrict__ wwt) {
  int n = blockIdx.x * 256 + threadIdx.x;
  float om[27];
#pragma unroll
  for (int ch = 0; ch < 27; ++ch) {
    float s = b_off[ch];
#pragma unroll
    for (int p = 0; p < 4; ++p)
      s += om_part[((size_t)p * 27 + ch) * NPIX + n];
    om[ch] = s;
  }
  int hw = n % HWSZ;
  int h = hw / WW;
  int w = hw - h * WW;
#pragma unroll
  for (int k = 0; k < 9; ++k) {
    float dy = om[2 * k];
    float dx = om[2 * k + 1];
    float mk = 1.f / (1.f + __expf(-om[18 + k]));
    float py = dy + (float)(h - 1 + k / 3);
    float px = dx + (float)(w - 1 + k % 3);
    float y0f = floorf(py), x0f = floorf(px);
    int y0 = (int)y0f, x0 = (int)x0f;
    float wy1 = py - y0f, wx1 = px - x0f;
    float wy0 = 1.f - wy1, wx0 = 1.f - wx1;
    bool vy0 = (y0 >= 0) && (y0 <= HH - 1);
    bool vy1 = (y0 + 1 >= 0) && (y0 + 1 <= HH - 1);
    bool vx0 = (x0 >= 0) && (x0 <= WW - 1);
    bool vx1 = (x0 + 1 >= 0) && (x0 + 1 <= WW - 1);
    int yc0 = min(max(y0, 0), HH - 1), yc1 = min(max(y0 + 1, 0), HH - 1);
    int xc0 = min(max(x0, 0), WW - 1), xc1 = min(max(x0 + 1, 0), WW - 1);
    float w00 = wy0 * wx0 * mk * (float)(vy0 && vx0);
    float w01 = wy0 * wx1 * mk * (float)(vy0 && vx1);
    float w10 = wy1 * wx0 * mk * (float)(vy1 && vx0);
    float w11 = wy1 * wx1 * mk * (float)(vy1 && vx1);
    uint_t i00 = (uint_t)(yc0 * WW + xc0), i01 = (uint_t)(yc0 * WW + xc1);
    uint_t i10 = (uint_t)(yc1 * WW + xc0), i11 = (uint_t)(yc1 * WW + xc1);
    widx[(size_t)n * 9 + k] = make_uint2(i00 | (i01 << 16), i10 | (i11 << 16));
    wwt[(size_t)n * 9 + k] = make_float4(w00, w01, w10, w11);
  }
}

// ---------------- 4) fused sample + GEMM ----------------
// out[b,o,hw] = sum_{kk} W9[o,kk] * S[kk, n],  S generated by bilinear gather.
// Grid: x = N-tile (288), y = M-tile (2). 256 threads = 4 waves, wave tile 64x32.
__global__ __launch_bounds__(256) void dcn_gemm(
    const float* __restrict__ x, const ushort_t* __restrict__ w9bf,
    const uint2* __restrict__ widx, const float4* __restrict__ wwt,
    const float* __restrict__ b_dcn, float* __restrict__ out) {
  __shared__ __align__(16) ushort_t Alds[4 * A_STRIDE];
  __shared__ __align__(16) ushort_t Slds[4 * S_STRIDE];
  __shared__ __align__(16) uint2 idx_l[BN * 9];
  __shared__ __align__(16) float4 wt_l[BN * 9];

  const int tid = threadIdx.x;
  const int nt = blockIdx.x;        // 0..287
  const int mt = blockIdx.y;        // 0..1
  const int p0 = nt * BN;
  const int m0 = mt * BM;
  const int bimg = p0 / HWSZ;       // uniform per tile (HWSZ % BN == 0)
  const float* xb = x + (size_t)bimg * CI * HWSZ;

  // load prep tables for this pixel tile (contiguous: [p0*9 .. p0*9+576))
  for (int e = tid; e < BN * 9; e += 256) {
    idx_l[e] = widx[(size_t)p0 * 9 + e];
    wt_l[e] = wwt[(size_t)p0 * 9 + e];
  }

  f32x4 acc[4][2];
#pragma unroll
  for (int i = 0; i < 4; ++i)
#pragma unroll
    for (int j = 0; j < 2; ++j) acc[i][j] = (f32x4){0.f, 0.f, 0.f, 0.f};

  const int lane = tid & 63, wid = tid >> 6;
  const int wr = wid >> 1, wc = wid & 1;        // wave tile: rows wr*64, cols wc*32
  const int lg = lane >> 4, lm = lane & 15;

  // A staging: thread -> (m = tid>>1, k half = (tid&1)*16)
  const int sa_m = tid >> 1, sa_kh = tid & 1;
  const ushort_t* aglob = w9bf + (size_t)(m0 + sa_m) * KTOT + sa_kh * 16;
  // S generation: thread -> (pixel = tid&63, kgroup = tid>>6)
  const int sp = tid & 63, skg = tid >> 6;

  __syncthreads();  // prep tables visible

  for (int ko = 0; ko < NCHUNK; ++ko) {
    // ---- stage A tile (bf16, fragment order [kg][m][8]) ----
    {
      const ushort_t* src = aglob + ko * BK;
      uint4 v0 = *(const uint4*)(src);
      uint4 v1 = *(const uint4*)(src + 8);
      int kg0 = sa_kh * 2;
      *(uint4*)&Alds[kg0 * A_STRIDE + sa_m * 8] = v0;
      *(uint4*)&Alds[(kg0 + 1) * A_STRIDE + sa_m * 8] = v1;
    }
    // ---- generate S tile: 8 kk rows per thread, one pixel ----
    {
      ushort_t sv[8] __attribute__((aligned(16)));
      int base_kk = ko * BK + skg * 8;
#pragma unroll
      for (int j = 0; j < 8; ++j) {
        int kk = base_kk + j;
        int c = kk / 9;
        int k = kk - c * 9;
        uint2 id = idx_l[sp * 9 + k];
        float4 wv = wt_l[sp * 9 + k];
        const float* xc = xb + (size_t)c * HWSZ;
        float v = wv.x * xc[id.x & 0xffffu] + wv.y * xc[id.x >> 16] +
                  wv.z * xc[id.y & 0xffffu] + wv.w * xc[id.y >> 16];
        sv[j] = f2bf(v);
      }
      *(uint4*)&Slds[skg * S_STRIDE + sp * 8] = *(const uint4*)sv;
    }
    __syncthreads();
    // ---- MFMA ----
    bf16x8 af[4], bfr[2];
#pragma unroll
    for (int mi = 0; mi < 4; ++mi)
      af[mi] = *(const bf16x8*)&Alds[lg * A_STRIDE + (wr * 64 + mi * 16 + lm) * 8];
#pragma unroll
    for (int ni = 0; ni < 2; ++ni)
      bfr[ni] = *(const bf16x8*)&Slds[lg * S_STRIDE + (wc * 32 + ni * 16 + lm) * 8];
#pragma unroll
    for (int mi = 0; mi < 4; ++mi)
#pragma unroll
      for (int ni = 0; ni < 2; ++ni)
        acc[mi][ni] = __builtin_amdgcn_mfma_f32_16x16x32_bf16(af[mi], bfr[ni], acc[mi][ni], 0, 0, 0);
    __syncthreads();
  }

  // ---- epilogue: + b_dcn, store pre-BN fp32 ----
#pragma unroll
  for (int mi = 0; mi < 4; ++mi) {
    int obase = m0 + wr * 64 + mi * 16 + lg * 4;
#pragma unroll
    for (int ni = 0; ni < 2; ++ni) {
      int hw = p0 - bimg * HWSZ + wc * 32 + ni * 16 + lm;
#pragma unroll
      for (int r = 0; r < 4; ++r) {
        int o = obase + r;
        out[((size_t)(bimg * CO + o)) * HWSZ + hw] = acc[mi][ni][r] + b_dcn[o];
      }
    }
  }
}

// ---------------- 5) BN stats ----------------
// ss[o] = rstd*gamma, ss[256+o] = beta - mean*rstd*gamma
__global__ void bn_stats(const float* __restrict__ out, const float* __restrict__ gamma,
                         const float* __restrict__ beta, float* __restrict__ ss) {
  int o = blockIdx.x;
  int tid = threadIdx.x;
  float s = 0.f, sq = 0.f;
#pragma unroll
  for (int b = 0; b < NB; ++b) {
    const float* p = out + ((size_t)(b * CO + o)) * HWSZ;
    for (int j = tid; j < HWSZ; j += 256) {
      float v = p[j];
      s += v;
      sq += v * v;
    }
  }
#pragma unroll
  for (int off = 32; off > 0; off >>= 1) {
    s += __shfl_xor(s, off);
    sq += __shfl_xor(sq, off);
  }
  __shared__ float rs[4], rq[4];
  if ((tid & 63) == 0) { rs[tid >> 6] = s; rq[tid >> 6] = sq; }
  __syncthreads();
  if (tid == 0) {
    s = rs[0] + rs[1] + rs[2] + rs[3];
    sq = rq[0] + rq[1] + rq[2] + rq[3];
    float mean = s * (1.f / (float)NPIX);
    float var = sq * (1.f / (float)NPIX) - mean * mean;
    float rstd = rsqrtf(var + 1e-5f);
    float sc = rstd * gamma[o];
    ss[o] = sc;
    ss[CO + o] = beta[o] - mean * sc;
  }
}

// ---------------- 6) BN apply + ReLU ----------------
__global__ void bn_apply(float* __restrict__ out, const float* __restrict__ ss) {
  int i = blockIdx.x * 256 + threadIdx.x;  // float4 index, exact grid
  float4 v = ((float4*)out)[i];
  int o = (i / (HWSZ / 4)) & 255;
  float sc = ss[o], sh = ss[CO + o];
  v.x = fmaxf(v.x * sc + sh, 0.f);
  v.y = fmaxf(v.y * sc + sh, 0.f);
  v.z = fmaxf(v.z * sc + sh, 0.f);
  v.w = fmaxf(v.w * sc + sh, 0.f);
  ((float4*)out)[i] = v;
}

extern "C" void kernel_launch(void* const* d_in, const int* in_sizes, int n_in,
                              void* d_out, int out_size, void* d_ws, size_t ws_size,
                              hipStream_t stream) {
  const float* x = (const float*)d_in[0];
  const float* w_off = (const float*)d_in[1];
  const float* b_off = (const float*)d_in[2];
  const float* w_dcn = (const float*)d_in[3];
  const float* b_dcn = (const float*)d_in[4];
  const float* gamma = (const float*)d_in[5];
  const float* beta = (const float*)d_in[6];
  float* out = (float*)d_out;

  // ws layout (bytes, 256-aligned): total ~13.2 MB
  char* ws = (char*)d_ws;
  float* om_part = (float*)(ws);                         // 4*27*18432 f = 7,962,624 B
  uint2* widx = (uint2*)(ws + 7962624);                  // 165888*8  = 1,327,104 B
  float4* wwt = (float4*)(ws + 9289728);                 // 165888*16 = 2,654,208 B
  ushort_t* w9bf = (ushort_t*)(ws + 11943936);           // 589824*2  = 1,179,648 B
  float* ss = (float*)(ws + 13123584);                   // 512 f

  cvt_w9<<<(CO * KTOT + 255) / 256, 256, 0, stream>>>(w_dcn, w9bf, CO * KTOT);
  off_conv_part<<<dim3(NPIX / 256, 4), 256, 0, stream>>>(x, w_off, om_part);
  prep_kernel<<<NPIX / 256, 256, 0, stream>>>(om_part, b_off, widx, wwt);
  dcn_gemm<<<dim3(NPIX / BN, CO / BM), 256, 0, stream>>>(x, w9bf, widx, wwt, b_dcn, out);
  bn_stats<<<CO, 256, 0, stream>>>(out, gamma, beta, ss);
  bn_apply<<<(out_size / 4) / 256, 256, 0, stream>>>(out, ss);
}

// Round 2
// 424.160 us; speedup vs baseline: 1.2385x; 1.2385x over previous
//
#include <hip/hip_runtime.h>

// DeformConv fused pipeline, MI355X gfx950.
// Shapes (hard-coded per reference): B=2, Ci=Co=256, H=W=96.
// R2 changes vs R1:
//  - dcn_gemm: BM=256 (S generated ONCE), 512 thr / 8 waves, launch_bounds(512,2)
//    so VGPRs (<=128) allow 16 gathers in flight per thread per chunk.
//  - W pre-reordered into per-chunk LDS image -> A staged via global_load_lds x16.
//  - prep tables SoA [k][n] in global and [k][p] in LDS (bank-conflict-free).

typedef unsigned short ushort_t;
typedef unsigned int uint_t;
typedef __attribute__((ext_vector_type(8))) short bf16x8;
typedef __attribute__((ext_vector_type(4))) float f32x4;

#define HH 96
#define WW 96
#define HWSZ 9216
#define CI 256
#define CO 256
#define NB 2
#define NPIX 18432           // NB*HWSZ
#define KTOT 2304            // CI*9
#define BM 256
#define BN 64
#define BK 32
#define NCHUNK 72            // KTOT/BK

__device__ __forceinline__ ushort_t f2bf(float f) {
  unsigned int u = __float_as_uint(f);
  u += 0x7fffu + ((u >> 16) & 1u);   // RNE
  return (ushort_t)(u >> 16);
}

__device__ __forceinline__ void gload16(const void* g, void* l) {
  __builtin_amdgcn_global_load_lds(
      (const __attribute__((address_space(1))) unsigned int*)g,
      (__attribute__((address_space(3))) unsigned int*)l, 16, 0, 0);
}

// ---------------- 1) w_dcn -> bf16, reordered per-chunk [ko][kg][m][8] ----------------
__global__ void cvt_w9(const float* __restrict__ w, ushort_t* __restrict__ o) {
  int i = blockIdx.x * 256 + threadIdx.x;     // i = oo*KTOT + kk, grid exact (CO*KTOT)
  int oo = i / KTOT;
  int kk = i - oo * KTOT;
  int ko = kk >> 5, kg = (kk >> 3) & 3, j = kk & 7;
  o[ko * 8192 + kg * 2048 + oo * 8 + j] = f2bf(w[i]);
}

// ---------------- 2) offset conv partials ----------------
// om_part layout: [4 part][27 ch][NPIX]
__global__ void off_conv_part(const float* __restrict__ x, const float* __restrict__ w_off,
                              float* __restrict__ om_part) {
  int n = blockIdx.x * 256 + threadIdx.x;      // pixel, exact grid
  int part = blockIdx.y;                        // 0..3 -> ci chunk of 64
  int b = n / HWSZ;
  int hw = n - b * HWSZ;
  int h = hw / WW;
  int w = hw - h * WW;
  float acc[27];
#pragma unroll
  for (int i = 0; i < 27; ++i) acc[i] = 0.f;
  const float* xb = x + (size_t)b * CI * HWSZ;
  int ci0 = part * 64;
  for (int ci = ci0; ci < ci0 + 64; ++ci) {
    const float* xc = xb + (size_t)ci * HWSZ;
    float xv[9];
#pragma unroll
    for (int t = 0; t < 9; ++t) {
      int yy = h - 1 + t / 3;
      int xx = w - 1 + t % 3;
      bool ok = (yy >= 0) && (yy < HH) && (xx >= 0) && (xx < WW);
      xv[t] = ok ? xc[yy * WW + xx] : 0.f;
    }
    const float* wp = w_off + ci * 9;           // w_off[ch][ci][t]
#pragma unroll
    for (int ch = 0; ch < 27; ++ch) {
      const float* wc = wp + ch * 2304;
#pragma unroll
      for (int t = 0; t < 9; ++t) acc[ch] += xv[t] * wc[t];
    }
  }
  float* op = om_part + (size_t)part * 27 * NPIX;
#pragma unroll
  for (int ch = 0; ch < 27; ++ch) op[(size_t)ch * NPIX + n] = acc[ch];
}

// ---------------- 3) prep: coords -> corner idx + folded weights (SoA [k][n]) ----------------
__global__ void prep_kernel(const float* __restrict__ om_part, const float* __restrict__ b_off,
                            uint2* __restrict__ widx, float4* __restrict__ wwt) {
  int n = blockIdx.x * 256 + threadIdx.x;
  float om[27];
#pragma unroll
  for (int ch = 0; ch < 27; ++ch) {
    float s = b_off[ch];
#pragma unroll
    for (int p = 0; p < 4; ++p)
      s += om_part[((size_t)p * 27 + ch) * NPIX + n];
    om[ch] = s;
  }
  int hw = n % HWSZ;
  int h = hw / WW;
  int w = hw - h * WW;
#pragma unroll
  for (int k = 0; k < 9; ++k) {
    float dy = om[2 * k];
    float dx = om[2 * k + 1];
    float mk = 1.f / (1.f + __expf(-om[18 + k]));
    float py = dy + (float)(h - 1 + k / 3);
    float px = dx + (float)(w - 1 + k % 3);
    float y0f = floorf(py), x0f = floorf(px);
    int y0 = (int)y0f, x0 = (int)x0f;
    float wy1 = py - y0f, wx1 = px - x0f;
    float wy0 = 1.f - wy1, wx0 = 1.f - wx1;
    bool vy0 = (y0 >= 0) && (y0 <= HH - 1);
    bool vy1 = (y0 + 1 >= 0) && (y0 + 1 <= HH - 1);
    bool vx0 = (x0 >= 0) && (x0 <= WW - 1);
    bool vx1 = (x0 + 1 >= 0) && (x0 + 1 <= WW - 1);
    int yc0 = min(max(y0, 0), HH - 1), yc1 = min(max(y0 + 1, 0), HH - 1);
    int xc0 = min(max(x0, 0), WW - 1), xc1 = min(max(x0 + 1, 0), WW - 1);
    float w00 = wy0 * wx0 * mk * (float)(vy0 && vx0);
    float w01 = wy0 * wx1 * mk * (float)(vy0 && vx1);
    float w10 = wy1 * wx0 * mk * (float)(vy1 && vx0);
    float w11 = wy1 * wx1 * mk * (float)(vy1 && vx1);
    uint_t i00 = (uint_t)(yc0 * WW + xc0), i01 = (uint_t)(yc0 * WW + xc1);
    uint_t i10 = (uint_t)(yc1 * WW + xc0), i11 = (uint_t)(yc1 * WW + xc1);
    widx[(size_t)k * NPIX + n] = make_uint2(i00 | (i01 << 16), i10 | (i11 << 16));
    wwt[(size_t)k * NPIX + n] = make_float4(w00, w01, w10, w11);
  }
}

// ---------------- 4) fused sample + GEMM ----------------
// out[b,o,hw] = sum_kk W9[o,kk] * S[kk,n]. Grid: 288 N-tiles, BM=256 (all of Co).
// 512 threads = 8 waves, wave tile 64x32: wr=wid>>1 (M quadrant), wc=wid&1 (N half).
__global__ __launch_bounds__(512, 2) void dcn_gemm(
    const float* __restrict__ x, const ushort_t* __restrict__ w9r,
    const uint2* __restrict__ widx, const float4* __restrict__ wwt,
    const float* __restrict__ b_dcn, float* __restrict__ out) {
  __shared__ __align__(16) ushort_t Alds[8192];      // [kg][256][8] = 16 KB
  __shared__ __align__(16) ushort_t Slds[2048];      // [kg][64][8]  = 4 KB
  __shared__ __align__(16) uint2 idx_l[9][64];
  __shared__ __align__(16) float4 wt_l[9][64];

  const int tid = threadIdx.x;
  const int p0 = blockIdx.x * BN;
  const int bimg = p0 / HWSZ;                 // uniform per tile
  const int hw0 = p0 - bimg * HWSZ;
  const float* xb = x + (size_t)bimg * CI * HWSZ;

  // SoA prep tables for this pixel tile (coalesced)
  for (int e = tid; e < 9 * BN; e += 512) {
    int k = e >> 6, p = e & 63;
    idx_l[k][p] = widx[(size_t)k * NPIX + p0 + p];
    wt_l[k][p] = wwt[(size_t)k * NPIX + p0 + p];
  }

  f32x4 acc[4][2];
#pragma unroll
  for (int i = 0; i < 4; ++i)
#pragma unroll
    for (int j = 0; j < 2; ++j) acc[i][j] = (f32x4){0.f, 0.f, 0.f, 0.f};

  const int lane = tid & 63, wid = tid >> 6;
  const int wr = wid >> 1, wc = wid & 1;
  const int lg = lane >> 4, lm = lane & 15;
  // S generation mapping: 4 elems/thread
  const int sp = tid & 63;
  const int skg = (tid >> 6) & 3;
  const int shalf = tid >> 8;

  __syncthreads();  // prep tables visible

  for (int ko = 0; ko < NCHUNK; ++ko) {
    // ---- stage A tile directly to LDS (16 KB, 2 passes of 512x16B) ----
    {
      const ushort_t* ga = w9r + (size_t)ko * 8192 + tid * 8;
      gload16(ga, &Alds[wid * 512]);                 // wave-uniform LDS base
      gload16(ga + 4096, &Alds[4096 + wid * 512]);
    }
    // ---- generate S: 4 consecutive kk for one pixel, loads batched ----
    {
      float v[4];
      int kkb = ko * BK + skg * 8 + shalf * 4;
#pragma unroll
      for (int j = 0; j < 4; ++j) {
        int kk = kkb + j;
        int c = kk / 9;
        int k = kk - c * 9;
        uint2 id = idx_l[k][sp];
        float4 wv = wt_l[k][sp];
        const float* xc = xb + c * HWSZ;
        v[j] = wv.x * xc[id.x & 0xffffu] + wv.y * xc[id.x >> 16] +
               wv.z * xc[id.y & 0xffffu] + wv.w * xc[id.y >> 16];
      }
      uint2 pk;
      pk.x = (uint_t)f2bf(v[0]) | ((uint_t)f2bf(v[1]) << 16);
      pk.y = (uint_t)f2bf(v[2]) | ((uint_t)f2bf(v[3]) << 16);
      *(uint2*)&Slds[(skg * 64 + sp) * 8 + shalf * 4] = pk;
    }
    __syncthreads();   // drains vmcnt (A in LDS) + lgkmcnt (S written)
    // ---- MFMA ----
    bf16x8 af[4], bfr[2];
#pragma unroll
    for (int mi = 0; mi < 4; ++mi)
      af[mi] = *(const bf16x8*)&Alds[(lg * 256 + wr * 64 + mi * 16 + lm) * 8];
#pragma unroll
    for (int ni = 0; ni < 2; ++ni)
      bfr[ni] = *(const bf16x8*)&Slds[(lg * 64 + wc * 32 + ni * 16 + lm) * 8];
#pragma unroll
    for (int mi = 0; mi < 4; ++mi)
#pragma unroll
      for (int ni = 0; ni < 2; ++ni)
        acc[mi][ni] = __builtin_amdgcn_mfma_f32_16x16x32_bf16(af[mi], bfr[ni], acc[mi][ni], 0, 0, 0);
    __syncthreads();
  }

  // ---- epilogue: + b_dcn, store pre-BN fp32 ----
#pragma unroll
  for (int mi = 0; mi < 4; ++mi) {
    int obase = wr * 64 + mi * 16 + lg * 4;
#pragma unroll
    for (int ni = 0; ni < 2; ++ni) {
      int hw = hw0 + wc * 32 + ni * 16 + lm;
#pragma unroll
      for (int r = 0; r < 4; ++r) {
        int o = obase + r;
        out[((size_t)(bimg * CO + o)) * HWSZ + hw] = acc[mi][ni][r] + b_dcn[o];
      }
    }
  }
}

// ---------------- 5) BN stats ----------------
__global__ void bn_stats(const float* __restrict__ out, const float* __restrict__ gamma,
                         const float* __restrict__ beta, float* __restrict__ ss) {
  int o = blockIdx.x;
  int tid = threadIdx.x;
  float s = 0.f, sq = 0.f;
#pragma unroll
  for (int b = 0; b < NB; ++b) {
    const float* p = out + ((size_t)(b * CO + o)) * HWSZ;
    for (int j = tid; j < HWSZ; j += 256) {
      float v = p[j];
      s += v;
      sq += v * v;
    }
  }
#pragma unroll
  for (int off = 32; off > 0; off >>= 1) {
    s += __shfl_xor(s, off);
    sq += __shfl_xor(sq, off);
  }
  __shared__ float rs[4], rq[4];
  if ((tid & 63) == 0) { rs[tid >> 6] = s; rq[tid >> 6] = sq; }
  __syncthreads();
  if (tid == 0) {
    s = rs[0] + rs[1] + rs[2] + rs[3];
    sq = rq[0] + rq[1] + rq[2] + rq[3];
    float mean = s * (1.f / (float)NPIX);
    float var = sq * (1.f / (float)NPIX) - mean * mean;
    float rstd = rsqrtf(var + 1e-5f);
    float sc = rstd * gamma[o];
    ss[o] = sc;
    ss[CO + o] = beta[o] - mean * sc;
  }
}

// ---------------- 6) BN apply + ReLU ----------------
__global__ void bn_apply(float* __restrict__ out, const float* __restrict__ ss) {
  int i = blockIdx.x * 256 + threadIdx.x;  // float4 index, exact grid
  float4 v = ((float4*)out)[i];
  int o = (i / (HWSZ / 4)) & 255;
  float sc = ss[o], sh = ss[CO + o];
  v.x = fmaxf(v.x * sc + sh, 0.f);
  v.y = fmaxf(v.y * sc + sh, 0.f);
  v.z = fmaxf(v.z * sc + sh, 0.f);
  v.w = fmaxf(v.w * sc + sh, 0.f);
  ((float4*)out)[i] = v;
}

extern "C" void kernel_launch(void* const* d_in, const int* in_sizes, int n_in,
                              void* d_out, int out_size, void* d_ws, size_t ws_size,
                              hipStream_t stream) {
  const float* x = (const float*)d_in[0];
  const float* w_off = (const float*)d_in[1];
  const float* b_off = (const float*)d_in[2];
  const float* w_dcn = (const float*)d_in[3];
  const float* b_dcn = (const float*)d_in[4];
  const float* gamma = (const float*)d_in[5];
  const float* beta = (const float*)d_in[6];
  float* out = (float*)d_out;

  // ws layout (bytes): total ~13.2 MB
  char* ws = (char*)d_ws;
  float* om_part = (float*)(ws);                         // 4*27*18432*4 = 7,962,624 B
  uint2* widx = (uint2*)(ws + 7962624);                  // 9*18432*8  = 1,327,104 B
  float4* wwt = (float4*)(ws + 9289728);                 // 9*18432*16 = 2,654,208 B
  ushort_t* w9r = (ushort_t*)(ws + 11943936);            // 2304*256*2 = 1,179,648 B
  float* ss = (float*)(ws + 13123584);                   // 512 f

  cvt_w9<<<(CO * KTOT) / 256, 256, 0, stream>>>(w_dcn, w9r);
  off_conv_part<<<dim3(NPIX / 256, 4), 256, 0, stream>>>(x, w_off, om_part);
  prep_kernel<<<NPIX / 256, 256, 0, stream>>>(om_part, b_off, widx, wwt);
  dcn_gemm<<<NPIX / BN, 512, 0, stream>>>(x, w9r, widx, wwt, b_dcn, out);
  bn_stats<<<CO, 256, 0, stream>>>(out, gamma, beta, ss);
  bn_apply<<<(out_size / 4) / 256, 256, 0, stream>>>(out, ss);
}

// Round 3
// 314.833 us; speedup vs baseline: 1.6686x; 1.3473x over previous
//
#include <hip/hip_runtime.h>

// DeformConv fused pipeline, MI355X gfx950.
// Shapes (hard-coded per reference): B=2, Ci=Co=256, H=W=96.
// R3 changes vs R2 (dcn_gemm was 260us, latency-bound: MfmaUtil 3%, VALU 14%):
//  - bilinear via 2x float2 row-pair loads (8 gather addrs/thread/chunk, was 16);
//    prep folds clamp/validity/mask into 4 weights + packed row offsets.
//  - software pipeline: prefetch gathers+A-stage for ko+1 issued before barrier,
//    consumed next iteration (loads land across the barrier drain).
//  - launch_bounds(512,4): VGPR<=128, LDS 51KB -> 2 blocks/CU, all 288 resident.

typedef unsigned short ushort_t;
typedef unsigned int uint_t;
typedef __attribute__((ext_vector_type(8))) short bf16x8;
typedef __attribute__((ext_vector_type(4))) float f32x4;
typedef __attribute__((ext_vector_type(2), aligned(4))) float f32x2a;  // 4B-aligned float2

#define HH 96
#define WW 96
#define HWSZ 9216
#define CI 256
#define CO 256
#define NB 2
#define NPIX 18432           // NB*HWSZ
#define KTOT 2304            // CI*9
#define BM 256
#define BN 64
#define BK 32
#define NCHUNK 72            // KTOT/BK

__device__ __forceinline__ ushort_t f2bf(float f) {
  unsigned int u = __float_as_uint(f);
  u += 0x7fffu + ((u >> 16) & 1u);   // RNE
  return (ushort_t)(u >> 16);
}

__device__ __forceinline__ void gload16(const void* g, void* l) {
  __builtin_amdgcn_global_load_lds(
      (const __attribute__((address_space(1))) unsigned int*)g,
      (__attribute__((address_space(3))) unsigned int*)l, 16, 0, 0);
}

// ---------------- 1) w_dcn -> bf16, reordered per-chunk [ko][kg][m][8] ----------------
__global__ void cvt_w9(const float* __restrict__ w, ushort_t* __restrict__ o) {
  int i = blockIdx.x * 256 + threadIdx.x;     // i = oo*KTOT + kk, grid exact (CO*KTOT)
  int oo = i / KTOT;
  int kk = i - oo * KTOT;
  int ko = kk >> 5, kg = (kk >> 3) & 3, j = kk & 7;
  o[ko * 8192 + kg * 2048 + oo * 8 + j] = f2bf(w[i]);
}

// ---------------- 2) offset conv partials ----------------
// om_part layout: [4 part][27 ch][NPIX]
__global__ void off_conv_part(const float* __restrict__ x, const float* __restrict__ w_off,
                              float* __restrict__ om_part) {
  int n = blockIdx.x * 256 + threadIdx.x;      // pixel, exact grid
  int part = blockIdx.y;                        // 0..3 -> ci chunk of 64
  int b = n / HWSZ;
  int hw = n - b * HWSZ;
  int h = hw / WW;
  int w = hw - h * WW;
  float acc[27];
#pragma unroll
  for (int i = 0; i < 27; ++i) acc[i] = 0.f;
  const float* xb = x + (size_t)b * CI * HWSZ;
  int ci0 = part * 64;
  for (int ci = ci0; ci < ci0 + 64; ++ci) {
    const float* xc = xb + (size_t)ci * HWSZ;
    float xv[9];
#pragma unroll
    for (int t = 0; t < 9; ++t) {
      int yy = h - 1 + t / 3;
      int xx = w - 1 + t % 3;
      bool ok = (yy >= 0) && (yy < HH) && (xx >= 0) && (xx < WW);
      xv[t] = ok ? xc[yy * WW + xx] : 0.f;
    }
    const float* wp = w_off + ci * 9;           // w_off[ch][ci][t]
#pragma unroll
    for (int ch = 0; ch < 27; ++ch) {
      const float* wc = wp + ch * 2304;
#pragma unroll
      for (int t = 0; t < 9; ++t) acc[ch] += xv[t] * wc[t];
    }
  }
  float* op = om_part + (size_t)part * 27 * NPIX;
#pragma unroll
  for (int ch = 0; ch < 27; ++ch) op[(size_t)ch * NPIX + n] = acc[ch];
}

// ---------------- 3) prep: coords -> row-pair offsets + folded weights (SoA [k][n]) ----------------
// offs[k][n] = (yc0*96+xa) | (yc1*96+xa)<<16 ; wts[k][n] = {wa0,wb0,wa1,wb1}
// so that sample = wa0*x[o0] + wb0*x[o0+1] + wa1*x[o1] + wb1*x[o1+1].
__global__ void prep_kernel(const float* __restrict__ om_part, const float* __restrict__ b_off,
                            uint_t* __restrict__ offs, float4* __restrict__ wts) {
  int n = blockIdx.x * 256 + threadIdx.x;
  float om[27];
#pragma unroll
  for (int ch = 0; ch < 27; ++ch) {
    float s = b_off[ch];
#pragma unroll
    for (int p = 0; p < 4; ++p)
      s += om_part[((size_t)p * 27 + ch) * NPIX + n];
    om[ch] = s;
  }
  int hw = n % HWSZ;
  int h = hw / WW;
  int w = hw - h * WW;
#pragma unroll
  for (int k = 0; k < 9; ++k) {
    float dy = om[2 * k];
    float dx = om[2 * k + 1];
    float mk = 1.f / (1.f + __expf(-om[18 + k]));
    float py = dy + (float)(h - 1 + k / 3);
    float px = dx + (float)(w - 1 + k % 3);
    float y0f = floorf(py), x0f = floorf(px);
    int y0 = (int)y0f, x0 = (int)x0f;
    float wy1 = py - y0f, wx1 = px - x0f;
    float wy0 = 1.f - wy1, wx0 = 1.f - wx1;
    float vy0 = (y0 >= 0 && y0 <= HH - 1) ? 1.f : 0.f;
    float vy1 = (y0 + 1 >= 0 && y0 + 1 <= HH - 1) ? 1.f : 0.f;
    int yc0 = min(max(y0, 0), HH - 1), yc1 = min(max(y0 + 1, 0), HH - 1);
    int xa = min(max(x0, 0), WW - 2);
    float a_, b_;
    if (x0 >= 0 && x0 <= WW - 2)      { a_ = wx0; b_ = wx1; }
    else if (x0 == -1)                { a_ = wx1; b_ = 0.f; }
    else if (x0 == WW - 1)            { a_ = 0.f; b_ = wx0; }
    else                              { a_ = 0.f; b_ = 0.f; }
    float s0 = mk * vy0 * wy0, s1 = mk * vy1 * wy1;
    offs[(size_t)k * NPIX + n] = (uint_t)(yc0 * WW + xa) | ((uint_t)(yc1 * WW + xa) << 16);
    wts[(size_t)k * NPIX + n] = make_float4(a_ * s0, b_ * s0, a_ * s1, b_ * s1);
  }
}

// ---------------- 4) fused sample + GEMM ----------------
// out[b,o,hw] = sum_kk W9[o,kk] * S[kk,n]. Grid: 288 N-tiles, BM=256 (all of Co).
// 512 threads = 8 waves, wave tile 64x32. Double-buffered LDS, 1-deep prefetch.
__global__ __launch_bounds__(512, 4) void dcn_gemm(
    const float* __restrict__ x, const ushort_t* __restrict__ w9r,
    const uint_t* __restrict__ offs, const float4* __restrict__ wts,
    const float* __restrict__ b_dcn, float* __restrict__ out) {
  __shared__ __align__(16) ushort_t Alds[2][8192];   // [buf][kg][256][8] = 32 KB
  __shared__ __align__(16) ushort_t Slds[2][2048];   // [buf][kg][64][8]  = 8 KB
  __shared__ uint_t off_l[9][64];                    // 2.25 KB
  __shared__ __align__(16) float4 wt_l[9][64];       // 9 KB

  const int tid = threadIdx.x;
  const int p0 = blockIdx.x * BN;
  const int bimg = p0 / HWSZ;                 // uniform per tile
  const int hw0 = p0 - bimg * HWSZ;
  const float* xb = x + (size_t)bimg * CI * HWSZ;

  // SoA prep tables for this pixel tile (coalesced)
  for (int e = tid; e < 9 * BN; e += 512) {
    int k = e >> 6, p = e & 63;
    off_l[k][p] = offs[(size_t)k * NPIX + p0 + p];
    wt_l[k][p] = wts[(size_t)k * NPIX + p0 + p];
  }

  f32x4 acc[4][2];
#pragma unroll
  for (int i = 0; i < 4; ++i)
#pragma unroll
    for (int j = 0; j < 2; ++j) acc[i][j] = (f32x4){0.f, 0.f, 0.f, 0.f};

  const int lane = tid & 63, wid = tid >> 6;
  const int wr = wid >> 1, wc = wid & 1;
  const int lg = lane >> 4, lm = lane & 15;
  const int sp = tid & 63;                    // pixel within tile
  const int skg = (tid >> 6) & 3;             // k-group 0..3
  const int shalf = tid >> 8;                 // 0/1 -> which 4 of the 8 kk

  // running (c,k) decomposition of this thread's first kk of the current chunk
  int kkb = skg * 8 + shalf * 4;
  int cb = kkb / 9, kb = kkb - cb * 9;

  __syncthreads();  // prep tables visible

  // ---- prologue: prefetch chunk 0 ----
  f32x2a r0[4], r1[4];
  {
    int c = cb, k = kb;
#pragma unroll
    for (int j = 0; j < 4; ++j) {
      uint_t o2 = off_l[k][sp];
      const float* xc = xb + c * HWSZ;
      r0[j] = *(const f32x2a*)(xc + (o2 & 0xffffu));
      r1[j] = *(const f32x2a*)(xc + (o2 >> 16));
      int kn = k + 1; c += (kn == 9); k = (kn == 9) ? 0 : kn;
    }
    const ushort_t* ga = w9r + tid * 8;
    gload16(ga, &Alds[0][wid * 512]);
    gload16(ga + 4096, &Alds[0][4096 + wid * 512]);
  }

  for (int ko = 0; ko < NCHUNK; ++ko) {
    const int cur = ko & 1, nxt = cur ^ 1;
    // ---- consume prefetched gathers -> S values -> LDS[cur] ----
    {
      float v[4];
      int k = kb;
#pragma unroll
      for (int j = 0; j < 4; ++j) {
        float4 wv = wt_l[k][sp];
        v[j] = wv.x * r0[j].x + wv.y * r0[j].y + wv.z * r1[j].x + wv.w * r1[j].y;
        int kn = k + 1; k = (kn == 9) ? 0 : kn;
      }
      uint2 pk;
      pk.x = (uint_t)f2bf(v[0]) | ((uint_t)f2bf(v[1]) << 16);
      pk.y = (uint_t)f2bf(v[2]) | ((uint_t)f2bf(v[3]) << 16);
      *(uint2*)&Slds[cur][(skg * 64 + sp) * 8 + shalf * 4] = pk;
    }
    // ---- prefetch chunk ko+1 (regs + A stage into [nxt]) ----
    if (ko < NCHUNK - 1) {
      cb += 3; kb += 5;
      if (kb >= 9) { kb -= 9; cb += 1; }
      int c = cb, k = kb;
#pragma unroll
      for (int j = 0; j < 4; ++j) {
        uint_t o2 = off_l[k][sp];
        const float* xc = xb + c * HWSZ;
        r0[j] = *(const f32x2a*)(xc + (o2 & 0xffffu));
        r1[j] = *(const f32x2a*)(xc + (o2 >> 16));
        int kn = k + 1; c += (kn == 9); k = (kn == 9) ? 0 : kn;
      }
      const ushort_t* ga = w9r + (size_t)(ko + 1) * 8192 + tid * 8;
      gload16(ga, &Alds[nxt][wid * 512]);
      gload16(ga + 4096, &Alds[nxt][4096 + wid * 512]);
    }
    __syncthreads();   // S[cur] visible; A[cur] (prev iter) + prefetch drained
    // ---- MFMA on [cur] ----
    bf16x8 af[4], bfr[2];
#pragma unroll
    for (int mi = 0; mi < 4; ++mi)
      af[mi] = *(const bf16x8*)&Alds[cur][(lg * 256 + wr * 64 + mi * 16 + lm) * 8];
#pragma unroll
    for (int ni = 0; ni < 2; ++ni)
      bfr[ni] = *(const bf16x8*)&Slds[cur][(lg * 64 + wc * 32 + ni * 16 + lm) * 8];
#pragma unroll
    for (int mi = 0; mi < 4; ++mi)
#pragma unroll
      for (int ni = 0; ni < 2; ++ni)
        acc[mi][ni] = __builtin_amdgcn_mfma_f32_16x16x32_bf16(af[mi], bfr[ni], acc[mi][ni], 0, 0, 0);
    __syncthreads();   // [nxt] writers may proceed only after all reads of... (next iter writes [cur])
  }

  // ---- epilogue: + b_dcn, store pre-BN fp32 ----
#pragma unroll
  for (int mi = 0; mi < 4; ++mi) {
    int obase = wr * 64 + mi * 16 + lg * 4;
#pragma unroll
    for (int ni = 0; ni < 2; ++ni) {
      int hw = hw0 + wc * 32 + ni * 16 + lm;
#pragma unroll
      for (int r = 0; r < 4; ++r) {
        int o = obase + r;
        out[((size_t)(bimg * CO + o)) * HWSZ + hw] = acc[mi][ni][r] + b_dcn[o];
      }
    }
  }
}

// ---------------- 5) BN stats ----------------
__global__ void bn_stats(const float* __restrict__ out, const float* __restrict__ gamma,
                         const float* __restrict__ beta, float* __restrict__ ss) {
  int o = blockIdx.x;
  int tid = threadIdx.x;
  float s = 0.f, sq = 0.f;
#pragma unroll
  for (int b = 0; b < NB; ++b) {
    const float* p = out + ((size_t)(b * CO + o)) * HWSZ;
    for (int j = tid; j < HWSZ; j += 256) {
      float v = p[j];
      s += v;
      sq += v * v;
    }
  }
#pragma unroll
  for (int off = 32; off > 0; off >>= 1) {
    s += __shfl_xor(s, off);
    sq += __shfl_xor(sq, off);
  }
  __shared__ float rs[4], rq[4];
  if ((tid & 63) == 0) { rs[tid >> 6] = s; rq[tid >> 6] = sq; }
  __syncthreads();
  if (tid == 0) {
    s = rs[0] + rs[1] + rs[2] + rs[3];
    sq = rq[0] + rq[1] + rq[2] + rq[3];
    float mean = s * (1.f / (float)NPIX);
    float var = sq * (1.f / (float)NPIX) - mean * mean;
    float rstd = rsqrtf(var + 1e-5f);
    float sc = rstd * gamma[o];
    ss[o] = sc;
    ss[CO + o] = beta[o] - mean * sc;
  }
}

// ---------------- 6) BN apply + ReLU ----------------
__global__ void bn_apply(float* __restrict__ out, const float* __restrict__ ss) {
  int i = blockIdx.x * 256 + threadIdx.x;  // float4 index, exact grid
  float4 v = ((float4*)out)[i];
  int o = (i / (HWSZ / 4)) & 255;
  float sc = ss[o], sh = ss[CO + o];
  v.x = fmaxf(v.x * sc + sh, 0.f);
  v.y = fmaxf(v.y * sc + sh, 0.f);
  v.z = fmaxf(v.z * sc + sh, 0.f);
  v.w = fmaxf(v.w * sc + sh, 0.f);
  ((float4*)out)[i] = v;
}

extern "C" void kernel_launch(void* const* d_in, const int* in_sizes, int n_in,
                              void* d_out, int out_size, void* d_ws, size_t ws_size,
                              hipStream_t stream) {
  const float* x = (const float*)d_in[0];
  const float* w_off = (const float*)d_in[1];
  const float* b_off = (const float*)d_in[2];
  const float* w_dcn = (const float*)d_in[3];
  const float* b_dcn = (const float*)d_in[4];
  const float* gamma = (const float*)d_in[5];
  const float* beta = (const float*)d_in[6];
  float* out = (float*)d_out;

  // ws layout (bytes): total ~12.5 MB
  char* ws = (char*)d_ws;
  float* om_part = (float*)(ws);                         // 4*27*18432*4 = 7,962,624 B
  uint_t* offs = (uint_t*)(ws + 7962624);                // 9*18432*4  =   663,552 B
  float4* wts = (float4*)(ws + 8626176);                 // 9*18432*16 = 2,654,208 B
  ushort_t* w9r = (ushort_t*)(ws + 11280384);            // 2304*256*2 = 1,179,648 B
  float* ss = (float*)(ws + 12460032);                   // 512 f

  cvt_w9<<<(CO * KTOT) / 256, 256, 0, stream>>>(w_dcn, w9r);
  off_conv_part<<<dim3(NPIX / 256, 4), 256, 0, stream>>>(x, w_off, om_part);
  prep_kernel<<<NPIX / 256, 256, 0, stream>>>(om_part, b_off, offs, wts);
  dcn_gemm<<<NPIX / BN, 512, 0, stream>>>(x, w9r, offs, wts, b_dcn, out);
  bn_stats<<<CO, 256, 0, stream>>>(out, gamma, beta, ss);
  bn_apply<<<(out_size / 4) / 256, 256, 0, stream>>>(out, ss);
}